// Round 1
// baseline (350.654 us; speedup 1.0000x reference)
//
#include <hip/hip_runtime.h>
#include <hip/hip_bf16.h>
#include <cstdint>

// ---------------- problem constants ----------------
#define BSZ   4
#define TSEQ  2048
#define DMOD  768
#define DCONV 384
#define DGRIF 384
#define DFFN  2048
#define BT    (BSZ*TSEQ)          // 8192
#define NG1   1920                // 2*DCONV + 3*DGRIF
#define EPS_  1e-6f

typedef __bf16 bf16;
typedef __bf16 bf16x8 __attribute__((ext_vector_type(8)));
typedef float  f32x4  __attribute__((ext_vector_type(4)));

__device__ __forceinline__ float sigmoidf_(float x) { return 1.f / (1.f + __expf(-x)); }

// async global->LDS, 16B per lane; LDS dest must be wave-uniform base
__device__ __forceinline__ void gload_lds16(const void* g, void* l) {
  __builtin_amdgcn_global_load_lds(
      (const __attribute__((address_space(1))) void*)(uintptr_t)g,
      (__attribute__((address_space(3))) void*)(uint32_t)(uintptr_t)l,
      16, 0, 0);
}

// ---------------- weight transpose + bf16 cast ----------------
// W: [R][C] fp32 row-major  ->  Wt: [C][R] bf16 row-major (row stride R)
__global__ __launch_bounds__(256) void transpose_bf16_kernel(
    const float* __restrict__ W, bf16* __restrict__ Wt, int R, int C)
{
  __shared__ float tile[32][33];
  const int tc = blockIdx.x * 32;   // input col tile
  const int tr = blockIdx.y * 32;   // input row tile
  const int lx = threadIdx.x;       // 0..31
  const int ly = threadIdx.y;       // 0..7
  #pragma unroll
  for (int i = ly; i < 32; i += 8) {
    int r = tr + i, c = tc + lx;
    tile[i][lx] = (r < R && c < C) ? W[(size_t)r * C + c] : 0.f;
  }
  __syncthreads();
  #pragma unroll
  for (int i = ly; i < 32; i += 8) {
    int oc = tc + i;    // output row (= input col)
    int orr = tr + lx;  // output col (= input row)
    if (oc < C && orr < R) Wt[(size_t)oc * R + orr] = (bf16)tile[lx][i];
  }
}

// ---------------- rmsnorm (x fp32 -> xn bf16) ----------------
__global__ __launch_bounds__(256) void rmsnorm_in_kernel(
    const float* __restrict__ x, const float* __restrict__ w, bf16* __restrict__ out)
{
  __shared__ float sbuf[4];
  const int row = blockIdx.x;
  const int tid = threadIdx.x;
  const float* xr = x + (size_t)row * DMOD;
  float v0 = xr[tid], v1 = xr[tid + 256], v2 = xr[tid + 512];
  float s = v0*v0 + v1*v1 + v2*v2;
  #pragma unroll
  for (int o = 32; o > 0; o >>= 1) s += __shfl_down(s, o, 64);
  if ((tid & 63) == 0) sbuf[tid >> 6] = s;
  __syncthreads();
  float tot = sbuf[0] + sbuf[1] + sbuf[2] + sbuf[3];
  float rms = rsqrtf(tot * (1.f / (float)DMOD) + EPS_);
  bf16* orow = out + (size_t)row * DMOD;
  orow[tid]       = (bf16)(v0 * rms * w[tid]);
  orow[tid + 256] = (bf16)(v1 * rms * w[tid + 256]);
  orow[tid + 512] = (bf16)(v2 * rms * w[tid + 512]);
}

// ---------------- MFMA GEMM: C[M,N] = A[M,K](bf16) @ Bt[N,K](bf16)^T ----------------
// m97 structure: 128x128 tile, BK=64, 4 waves (2x2 of 64x64), global_load_lds width 16.
// EPI: 0 = store fp32 C. 1 = Hout = silu(P1) * acc (bf16). 2 = C += acc (residual add).
template <int EPI>
__global__ __launch_bounds__(256) void gemm_bt(
    const bf16* __restrict__ A, const bf16* __restrict__ Bt,
    float* __restrict__ C, const float* __restrict__ P1, bf16* __restrict__ Hout,
    int M, int N, int K)
{
  __shared__ alignas(16) unsigned short As[128 * 64];
  __shared__ alignas(16) unsigned short Bs[128 * 64];

  const int tid  = threadIdx.x;
  const int wave = tid >> 6;
  const int lane = tid & 63;
  const int wr = wave >> 1, wc = wave & 1;
  const int m0 = blockIdx.y * 128, n0 = blockIdx.x * 128;

  f32x4 acc[4][4] = {};

  const int srow = lane >> 3;          // 0..7 (row within 8-row chunk)
  const int scol = (lane & 7) * 8;     // element offset within 64-wide row
  const int lr = lane & 15;
  const int lk = (lane >> 4) * 8;

  for (int k0 = 0; k0 < K; k0 += 64) {
    __syncthreads();   // previous compute done before LDS overwrite
    #pragma unroll
    for (int it = 0; it < 4; ++it) {
      const int chunk = wave * 4 + it;            // wave-uniform
      const int row = chunk * 8 + srow;
      gload_lds16(A  + (size_t)(m0 + row) * K + k0 + scol, (char*)As + chunk * 1024);
      gload_lds16(Bt + (size_t)(n0 + row) * K + k0 + scol, (char*)Bs + chunk * 1024);
    }
    __syncthreads();   // vmcnt(0) drain: staged tile visible
    #pragma unroll
    for (int kk = 0; kk < 2; ++kk) {
      bf16x8 af[4], bfr[4];
      #pragma unroll
      for (int i = 0; i < 4; ++i)
        af[i] = *reinterpret_cast<const bf16x8*>(&As[(wr*64 + i*16 + lr) * 64 + kk*32 + lk]);
      #pragma unroll
      for (int i = 0; i < 4; ++i)
        bfr[i] = *reinterpret_cast<const bf16x8*>(&Bs[(wc*64 + i*16 + lr) * 64 + kk*32 + lk]);
      #pragma unroll
      for (int mi = 0; mi < 4; ++mi)
        #pragma unroll
        for (int ni = 0; ni < 4; ++ni)
          acc[mi][ni] = __builtin_amdgcn_mfma_f32_16x16x32_bf16(af[mi], bfr[ni], acc[mi][ni], 0, 0, 0);
    }
  }

  // epilogue: C/D layout col=lane&15, row=(lane>>4)*4+reg  [m89/m91 verified]
  #pragma unroll
  for (int mi = 0; mi < 4; ++mi)
    #pragma unroll
    for (int ni = 0; ni < 4; ++ni)
      #pragma unroll
      for (int reg = 0; reg < 4; ++reg) {
        const int r = m0 + wr*64 + mi*16 + (lane >> 4) * 4 + reg;
        const int c = n0 + wc*64 + ni*16 + (lane & 15);
        const size_t off = (size_t)r * N + c;
        float v = acc[mi][ni][reg];
        if (EPI == 0) {
          C[off] = v;
        } else if (EPI == 1) {
          float p = P1[off];
          Hout[off] = (bf16)(p * sigmoidf_(p) * v);
        } else {
          C[off] += v;
        }
      }
}

// ---------------- causal depthwise conv (K=3) * silu(g) ----------------
__global__ __launch_bounds__(256) void conv_gate_kernel(
    const float* __restrict__ g1, const float* __restrict__ dw, bf16* __restrict__ mixin)
{
  const int idx = blockIdx.x * 256 + threadIdx.x;   // < BT*DCONV
  const int c  = idx % DCONV;
  const int bt = idx / DCONV;
  const int t  = bt & (TSEQ - 1);
  const float* row = g1 + (size_t)bt * NG1;
  float u2 = row[c];
  float u1 = (t >= 1) ? row[c - NG1]     : 0.f;
  float u0 = (t >= 2) ? row[c - 2 * NG1] : 0.f;
  float conv = u0 * dw[c*3] + u1 * dw[c*3 + 1] + u2 * dw[c*3 + 2];
  float g = row[DCONV + c];
  mixin[(size_t)bt * DMOD + c] = (bf16)(conv * (g * sigmoidf_(g)));
}

// ---------------- RG-LRU 2-pass chunked scan ----------------
#define NCH  32
#define CLEN 64   // TSEQ / NCH

__device__ __forceinline__ void lru_step(const float* row, int c, float coef,
                                         float& a, float& g)
{
  float v  = row[2*DCONV + c];
  float r  = sigmoidf_(row[2*DCONV + DGRIF + c]);
  float is = sigmoidf_(row[2*DCONV + 2*DGRIF + c]);
  float la = coef * r;
  a = __expf(la);
  g = sqrtf(fmaxf(1.f - __expf(2.f * la), EPS_)) * (is * v);
}

__global__ __launch_bounds__(256) void lru_pass1(
    const float* __restrict__ g1, const float* __restrict__ lam,
    float* __restrict__ cA, float* __restrict__ cB)
{
  const int idx = blockIdx.x * 256 + threadIdx.x;   // < BSZ*NCH*DGRIF
  const int c = idx % DGRIF;
  const int rest = idx / DGRIF;
  const int j = rest & (NCH - 1);
  const int b = rest / NCH;
  const float coef = -8.f * log1pf(__expf(lam[c]));
  const float* base = g1 + (size_t)(b * TSEQ + j * CLEN) * NG1;
  float A = 1.f, Bv = 0.f;
  #pragma unroll 4
  for (int t = 0; t < CLEN; ++t) {
    float a, g;
    lru_step(base + (size_t)t * NG1, c, coef, a, g);
    A *= a;
    Bv = a * Bv + g;
  }
  cA[((size_t)b * DGRIF + c) * NCH + j] = A;
  cB[((size_t)b * DGRIF + c) * NCH + j] = Bv;
}

__global__ __launch_bounds__(256) void lru_pass2(
    const float* __restrict__ g1, const float* __restrict__ lam,
    const float* __restrict__ cA, const float* __restrict__ cB,
    bf16* __restrict__ mixin)
{
  const int idx = blockIdx.x * 256 + threadIdx.x;
  const int c = idx % DGRIF;
  const int rest = idx / DGRIF;
  const int j = rest & (NCH - 1);
  const int b = rest / NCH;
  const float coef = -8.f * log1pf(__expf(lam[c]));
  // carry from preceding chunks
  float Hc = 0.f;
  const float* pa = cA + ((size_t)b * DGRIF + c) * NCH;
  const float* pb = cB + ((size_t)b * DGRIF + c) * NCH;
  for (int k = 0; k < j; ++k) Hc = pa[k] * Hc + pb[k];
  const float* base = g1 + (size_t)(b * TSEQ + j * CLEN) * NG1;
  bf16* mbase = mixin + (size_t)(b * TSEQ + j * CLEN) * DMOD + DCONV + c;
  #pragma unroll 4
  for (int t = 0; t < CLEN; ++t) {
    float a, g;
    lru_step(base + (size_t)t * NG1, c, coef, a, g);
    Hc = a * Hc + g;
    mbase[(size_t)t * DMOD] = (bf16)Hc;
  }
}

// ---------------- momentum residual + ffn rmsnorm ----------------
__global__ __launch_bounds__(256) void ew2_kernel(
    const float* __restrict__ x, const float* __restrict__ vin,
    const float* __restrict__ mixout, const float* __restrict__ log_beta,
    const float* __restrict__ ffn_w, float* __restrict__ outx,
    float* __restrict__ outv, bf16* __restrict__ normed)
{
  __shared__ float sbuf[4];
  const int row = blockIdx.x;
  const int tid = threadIdx.x;
  const float beta = sigmoidf_(log_beta[0]);
  const size_t base = (size_t)row * DMOD;
  float xv[3];
  float s = 0.f;
  #pragma unroll
  for (int k = 0; k < 3; ++k) {
    const int i = tid + k * 256;
    float vel = beta * vin[base + i] + mixout[base + i];
    float x1  = x[base + i] + vel;
    outv[base + i] = vel;
    outx[base + i] = x1;
    xv[k] = x1;
    s += x1 * x1;
  }
  #pragma unroll
  for (int o = 32; o > 0; o >>= 1) s += __shfl_down(s, o, 64);
  if ((tid & 63) == 0) sbuf[tid >> 6] = s;
  __syncthreads();
  float tot = sbuf[0] + sbuf[1] + sbuf[2] + sbuf[3];
  float rms = rsqrtf(tot * (1.f / (float)DMOD) + EPS_);
  #pragma unroll
  for (int k = 0; k < 3; ++k) {
    const int i = tid + k * 256;
    normed[base + i] = (bf16)(xv[k] * rms * ffn_w[i]);
  }
}

// ---------------- launcher ----------------
extern "C" void kernel_launch(void* const* d_in, const int* in_sizes, int n_in,
                              void* d_out, int out_size, void* d_ws, size_t ws_size,
                              hipStream_t stream)
{
  const float* x         = (const float*)d_in[0];
  const float* vel_in    = (const float*)d_in[1];
  const float* pre_w     = (const float*)d_in[2];
  const float* conv_in_w = (const float*)d_in[3];
  const float* conv_dw   = (const float*)d_in[4];
  const float* gv        = (const float*)d_in[5];
  const float* gr        = (const float*)d_in[6];
  const float* gi        = (const float*)d_in[7];
  const float* lam       = (const float*)d_in[8];
  const float* out_w     = (const float*)d_in[9];
  const float* log_beta  = (const float*)d_in[10];
  const float* ffn_w     = (const float*)d_in[11];
  const float* w1        = (const float*)d_in[12];
  const float* w3        = (const float*)d_in[13];
  const float* w2        = (const float*)d_in[14];

  char* ws = (char*)d_ws;
  size_t off = 0;
  auto alloc = [&](size_t bytes) { void* p = ws + off; off += (bytes + 255) & ~(size_t)255; return p; };

  bf16*  WT_G1  = (bf16*)alloc((size_t)NG1 * DMOD * 2);        //  2.95 MB [1920][768]
  bf16*  WT_OUT = (bf16*)alloc((size_t)DMOD * DMOD * 2);       //  1.18 MB [768][768]
  bf16*  WT_W1  = (bf16*)alloc((size_t)DFFN * DMOD * 2);       //  3.15 MB [2048][768]
  bf16*  WT_W3  = (bf16*)alloc((size_t)DFFN * DMOD * 2);       //  3.15 MB
  bf16*  WT_W2  = (bf16*)alloc((size_t)DMOD * DFFN * 2);       //  3.15 MB [768][2048]
  float* CA     = (float*)alloc((size_t)BSZ * DGRIF * NCH * 4);
  float* CB     = (float*)alloc((size_t)BSZ * DGRIF * NCH * 4);
  char*  R1     = (char*)alloc(75497472ull);  // XN(12.6M bf16) + G1(62.9M f32); reused as P1(67.1M f32)
  char*  R2     = (char*)alloc(37748736ull);  // MIXIN(12.6M bf16) + MIXOUT(25.2M f32); reused as H(33.6M bf16)
  bf16*  NORMED = (bf16*)alloc((size_t)BT * DMOD * 2);

  bf16*  XN     = (bf16*)R1;
  float* G1     = (float*)(R1 + (size_t)BT * DMOD * 2);
  float* P1     = (float*)R1;
  bf16*  MIXIN  = (bf16*)R2;
  float* MIXOUT = (float*)(R2 + (size_t)BT * DMOD * 2);
  bf16*  H      = (bf16*)R2;
  float* OUTX   = (float*)d_out;
  float* OUTV   = OUTX + (size_t)BT * DMOD;

  const dim3 tb(32, 8);
  // weight transposes -> bf16 [N][K]
  transpose_bf16_kernel<<<dim3(DMOD/32,  DMOD/32), tb, 0, stream>>>(conv_in_w, WT_G1, DMOD, DMOD);
  transpose_bf16_kernel<<<dim3(DGRIF/32, DMOD/32), tb, 0, stream>>>(gv, WT_G1 + (size_t)(2*DCONV) * DMOD, DMOD, DGRIF);
  transpose_bf16_kernel<<<dim3(DGRIF/32, DMOD/32), tb, 0, stream>>>(gr, WT_G1 + (size_t)(2*DCONV + DGRIF) * DMOD, DMOD, DGRIF);
  transpose_bf16_kernel<<<dim3(DGRIF/32, DMOD/32), tb, 0, stream>>>(gi, WT_G1 + (size_t)(2*DCONV + 2*DGRIF) * DMOD, DMOD, DGRIF);
  transpose_bf16_kernel<<<dim3(DMOD/32,  DMOD/32), tb, 0, stream>>>(out_w, WT_OUT, DMOD, DMOD);
  transpose_bf16_kernel<<<dim3(DFFN/32,  DMOD/32), tb, 0, stream>>>(w1, WT_W1, DMOD, DFFN);
  transpose_bf16_kernel<<<dim3(DFFN/32,  DMOD/32), tb, 0, stream>>>(w3, WT_W3, DMOD, DFFN);
  transpose_bf16_kernel<<<dim3(DMOD/32,  DFFN/32), tb, 0, stream>>>(w2, WT_W2, DFFN, DMOD);

  // pre-norm
  rmsnorm_in_kernel<<<BT, 256, 0, stream>>>(x, pre_w, XN);

  // GEMM1: [8192,768] @ [768,1920] -> G1
  gemm_bt<0><<<dim3(NG1/128, BT/128), 256, 0, stream>>>(XN, WT_G1, G1, nullptr, nullptr, BT, NG1, DMOD);

  // conv branch + RG-LRU branch -> MIXIN
  conv_gate_kernel<<<(BT * DCONV) / 256, 256, 0, stream>>>(G1, conv_dw, MIXIN);
  lru_pass1<<<(BSZ * NCH * DGRIF) / 256, 256, 0, stream>>>(G1, lam, CA, CB);
  lru_pass2<<<(BSZ * NCH * DGRIF) / 256, 256, 0, stream>>>(G1, lam, CA, CB, MIXIN);

  // GEMM2: mixer out-proj
  gemm_bt<0><<<dim3(DMOD/128, BT/128), 256, 0, stream>>>(MIXIN, WT_OUT, MIXOUT, nullptr, nullptr, BT, DMOD, DMOD);

  // momentum residual + ffn rmsnorm (writes x1 and velocity to d_out)
  ew2_kernel<<<BT, 256, 0, stream>>>(x, vel_in, MIXOUT, log_beta, ffn_w, OUTX, OUTV, NORMED);

  // FFN
  gemm_bt<0><<<dim3(DFFN/128, BT/128), 256, 0, stream>>>(NORMED, WT_W1, P1, nullptr, nullptr, BT, DFFN, DMOD);
  gemm_bt<1><<<dim3(DFFN/128, BT/128), 256, 0, stream>>>(NORMED, WT_W3, nullptr, P1, H, BT, DFFN, DMOD);
  gemm_bt<2><<<dim3(DMOD/128, BT/128), 256, 0, stream>>>(H, WT_W2, OUTX, nullptr, nullptr, BT, DMOD, DFFN);
}

// Round 3
// 323.376 us; speedup vs baseline: 1.0844x; 1.0844x over previous
//
#include <hip/hip_runtime.h>
#include <hip/hip_bf16.h>
#include <cstdint>

// ---------------- problem constants ----------------
#define BSZ   4
#define TSEQ  2048
#define DMOD  768
#define DCONV 384
#define DGRIF 384
#define DFFN  2048
#define BT    (BSZ*TSEQ)          // 8192
#define NG1   1920                // 2*DCONV + 3*DGRIF
#define EPS_  1e-6f

typedef __bf16 bf16;
typedef __bf16 bf16x8 __attribute__((ext_vector_type(8)));
typedef float  f32x4  __attribute__((ext_vector_type(4)));

__device__ __forceinline__ float sigmoidf_(float x) { return 1.f / (1.f + __expf(-x)); }

// async global->LDS, 16B per lane; LDS dest must be wave-uniform base
__device__ __forceinline__ void gload_lds16(const void* g, void* l) {
  __builtin_amdgcn_global_load_lds(
      (const __attribute__((address_space(1))) void*)(uintptr_t)g,
      (__attribute__((address_space(3))) void*)(uint32_t)(uintptr_t)l,
      16, 0, 0);
}

// bijective XCD swizzle: nwg % 8 == 0 for all our grids
__device__ __forceinline__ int swz_wg() {
  const int nwg = gridDim.x;
  const int bid = blockIdx.x;
  const int cpx = nwg >> 3;
  return (bid & 7) * cpx + (bid >> 3);
}

// ---------------- weight transpose + bf16 cast ----------------
// W: [R][C] fp32  ->  Wt[out_row][R] bf16.  MODE 0: out_row = c.
// MODE 1: out_row = (c/64)*128 + half + (c%64)   (w1/w3 interleave for fused FFN)
template <int MODE>
__global__ __launch_bounds__(256) void transpose_bf16_kernel(
    const float* __restrict__ W, bf16* __restrict__ Wt, int R, int C, int half)
{
  __shared__ float tile[32][33];
  const int tc = blockIdx.x * 32;   // input col tile
  const int tr = blockIdx.y * 32;   // input row tile
  const int lx = threadIdx.x;       // 0..31
  const int ly = threadIdx.y;       // 0..7
  #pragma unroll
  for (int i = ly; i < 32; i += 8) {
    int r = tr + i, c = tc + lx;
    tile[i][lx] = (r < R && c < C) ? W[(size_t)r * C + c] : 0.f;
  }
  __syncthreads();
  #pragma unroll
  for (int i = ly; i < 32; i += 8) {
    int oc = tc + i;    // input col
    int orr = tr + lx;  // input row -> output col
    if (oc < C && orr < R) {
      int orow = (MODE == 0) ? oc : ((oc >> 6) << 7) + half + (oc & 63);
      Wt[(size_t)orow * R + orr] = (bf16)tile[lx][i];
    }
  }
}

// ---------------- rmsnorm (x fp32 -> out bf16) ----------------
__global__ __launch_bounds__(256) void rmsnorm_kernel(
    const float* __restrict__ x, const float* __restrict__ w, bf16* __restrict__ out)
{
  __shared__ float sbuf[4];
  const int row = blockIdx.x;
  const int tid = threadIdx.x;
  const float* xr = x + (size_t)row * DMOD;
  float v0 = xr[tid], v1 = xr[tid + 256], v2 = xr[tid + 512];
  float s = v0*v0 + v1*v1 + v2*v2;
  #pragma unroll
  for (int o = 32; o > 0; o >>= 1) s += __shfl_down(s, o, 64);
  if ((tid & 63) == 0) sbuf[tid >> 6] = s;
  __syncthreads();
  float tot = sbuf[0] + sbuf[1] + sbuf[2] + sbuf[3];
  float rms = rsqrtf(tot * (1.f / (float)DMOD) + EPS_);
  bf16* orow = out + (size_t)row * DMOD;
  orow[tid]       = (bf16)(v0 * rms * w[tid]);
  orow[tid + 256] = (bf16)(v1 * rms * w[tid + 256]);
  orow[tid + 512] = (bf16)(v2 * rms * w[tid + 512]);
}

// ---------------- wide GEMM: 128x128 tile, bf16 C out (GEMM1) ----------------
__global__ __launch_bounds__(256) void gemm_w128(
    const bf16* __restrict__ A, const bf16* __restrict__ Bt, bf16* __restrict__ C,
    int M, int N, int K, int nx)
{
  __shared__ alignas(16) unsigned short As[128 * 64];
  __shared__ alignas(16) unsigned short Bs[128 * 64];

  const int wg = swz_wg();
  const int m0 = (wg / nx) * 128, n0 = (wg % nx) * 128;
  const int tid  = threadIdx.x;
  const int wave = tid >> 6;
  const int lane = tid & 63;
  const int wr = wave >> 1, wc = wave & 1;

  f32x4 acc[4][4] = {};
  const int srow = lane >> 3;
  const int scol = (lane & 7) * 8;
  const int lr = lane & 15;
  const int lk = (lane >> 4) * 8;

  for (int k0 = 0; k0 < K; k0 += 64) {
    __syncthreads();
    #pragma unroll
    for (int it = 0; it < 4; ++it) {
      const int chunk = wave * 4 + it;
      const int row = chunk * 8 + srow;
      gload_lds16(A  + (size_t)(m0 + row) * K + k0 + scol, (char*)As + chunk * 1024);
      gload_lds16(Bt + (size_t)(n0 + row) * K + k0 + scol, (char*)Bs + chunk * 1024);
    }
    __syncthreads();
    #pragma unroll
    for (int kk = 0; kk < 2; ++kk) {
      bf16x8 af[4], bfr[4];
      #pragma unroll
      for (int i = 0; i < 4; ++i)
        af[i] = *reinterpret_cast<const bf16x8*>(&As[(wr*64 + i*16 + lr) * 64 + kk*32 + lk]);
      #pragma unroll
      for (int i = 0; i < 4; ++i)
        bfr[i] = *reinterpret_cast<const bf16x8*>(&Bs[(wc*64 + i*16 + lr) * 64 + kk*32 + lk]);
      #pragma unroll
      for (int mi = 0; mi < 4; ++mi)
        #pragma unroll
        for (int ni = 0; ni < 4; ++ni)
          acc[mi][ni] = __builtin_amdgcn_mfma_f32_16x16x32_bf16(af[mi], bfr[ni], acc[mi][ni], 0, 0, 0);
    }
  }

  #pragma unroll
  for (int mi = 0; mi < 4; ++mi)
    #pragma unroll
    for (int ni = 0; ni < 4; ++ni)
      #pragma unroll
      for (int reg = 0; reg < 4; ++reg) {
        const int r = m0 + wr*64 + mi*16 + (lane >> 4) * 4 + reg;
        const int c = n0 + wc*64 + ni*16 + (lane & 15);
        C[(size_t)r * N + c] = (bf16)acc[mi][ni][reg];
      }
}

// ---------------- fused FFN GEMM: p1|p3 interleaved, epilogue silu(p1)*p3 ----------------
// Bt: [2*DFFN][K] with rows (j*128 + 0..63) = w1 cols j*64.., rows (j*128+64..127) = w3.
__global__ __launch_bounds__(256) void gemm_ffn13(
    const bf16* __restrict__ A, const bf16* __restrict__ Bt, bf16* __restrict__ H,
    int M, int K, int nx)   // nx = DFFN/64 = 32
{
  __shared__ alignas(16) unsigned short As[128 * 64];
  __shared__ alignas(16) unsigned short Bs[128 * 64];
  __shared__ alignas(16) bf16 comb[128 * 64];   // p3 pass-through (bf16)

  const int wg = swz_wg();
  const int m0 = (wg / nx) * 128;
  const int bx = wg % nx;
  const int n0 = bx * 128;            // row base into Bt
  const int tid  = threadIdx.x;
  const int wave = tid >> 6;
  const int lane = tid & 63;
  const int wr = wave >> 1, wc = wave & 1;

  f32x4 acc[4][4] = {};
  const int srow = lane >> 3;
  const int scol = (lane & 7) * 8;
  const int lr = lane & 15;
  const int lk = (lane >> 4) * 8;

  for (int k0 = 0; k0 < K; k0 += 64) {
    __syncthreads();
    #pragma unroll
    for (int it = 0; it < 4; ++it) {
      const int chunk = wave * 4 + it;
      const int row = chunk * 8 + srow;
      gload_lds16(A  + (size_t)(m0 + row) * K + k0 + scol, (char*)As + chunk * 1024);
      gload_lds16(Bt + (size_t)(n0 + row) * K + k0 + scol, (char*)Bs + chunk * 1024);
    }
    __syncthreads();
    #pragma unroll
    for (int kk = 0; kk < 2; ++kk) {
      bf16x8 af[4], bfr[4];
      #pragma unroll
      for (int i = 0; i < 4; ++i)
        af[i] = *reinterpret_cast<const bf16x8*>(&As[(wr*64 + i*16 + lr) * 64 + kk*32 + lk]);
      #pragma unroll
      for (int i = 0; i < 4; ++i)
        bfr[i] = *reinterpret_cast<const bf16x8*>(&Bs[(wc*64 + i*16 + lr) * 64 + kk*32 + lk]);
      #pragma unroll
      for (int mi = 0; mi < 4; ++mi)
        #pragma unroll
        for (int ni = 0; ni < 4; ++ni)
          acc[mi][ni] = __builtin_amdgcn_mfma_f32_16x16x32_bf16(af[mi], bfr[ni], acc[mi][ni], 0, 0, 0);
    }
  }

  // wc==1 waves hold p3 (w3 half); stash through LDS, wc==0 waves emit gated H
  if (wc == 1) {
    #pragma unroll
    for (int mi = 0; mi < 4; ++mi)
      #pragma unroll
      for (int ni = 0; ni < 4; ++ni)
        #pragma unroll
        for (int reg = 0; reg < 4; ++reg) {
          const int row = wr*64 + mi*16 + (lane >> 4) * 4 + reg;
          const int col = ni*16 + (lane & 15);
          comb[row * 64 + col] = (bf16)acc[mi][ni][reg];
        }
  }
  __syncthreads();
  if (wc == 0) {
    #pragma unroll
    for (int mi = 0; mi < 4; ++mi)
      #pragma unroll
      for (int ni = 0; ni < 4; ++ni)
        #pragma unroll
        for (int reg = 0; reg < 4; ++reg) {
          const int row = wr*64 + mi*16 + (lane >> 4) * 4 + reg;
          const int col = ni*16 + (lane & 15);
          float p3 = (float)comb[row * 64 + col];
          float p1 = acc[mi][ni][reg];
          H[(size_t)(m0 + row) * DFFN + bx * 64 + col] = (bf16)(p1 * sigmoidf_(p1) * p3);
        }
  }
}

// ---------------- narrow GEMM: 128x64 tile (N=768 GEMMs) ----------------
// EPI 0: momentum epilogue (vel = beta*vin + acc; x1 = x + vel -> outx, outv)
// EPI 1: C += acc (residual accumulate)
template <int EPI>
__global__ __launch_bounds__(256) void gemm_n64(
    const bf16* __restrict__ A, const bf16* __restrict__ Bt, float* __restrict__ C,
    const float* __restrict__ xin, const float* __restrict__ vin,
    float* __restrict__ outv, const float* __restrict__ log_beta,
    int M, int N, int K, int nx)
{
  __shared__ alignas(16) unsigned short As[128 * 64];   // 16 KB
  __shared__ alignas(16) unsigned short Bs[64 * 64];    //  8 KB

  const int wg = swz_wg();
  const int m0 = (wg / nx) * 128, n0 = (wg % nx) * 64;
  const int tid  = threadIdx.x;
  const int wave = tid >> 6;
  const int lane = tid & 63;
  const int wr = wave >> 1, wc = wave & 1;   // wave tile: 64 rows x 32 cols

  f32x4 acc[4][2] = {};
  const int srow = lane >> 3;
  const int scol = (lane & 7) * 8;
  const int lr = lane & 15;
  const int lk = (lane >> 4) * 8;

  for (int k0 = 0; k0 < K; k0 += 64) {
    __syncthreads();
    #pragma unroll
    for (int it = 0; it < 6; ++it) {
      const int chunk = wave * 6 + it;      // 0..23: 16 A-chunks then 8 B-chunks
      if (chunk < 16) {
        const int row = chunk * 8 + srow;
        gload_lds16(A + (size_t)(m0 + row) * K + k0 + scol, (char*)As + chunk * 1024);
      } else {
        const int row = (chunk - 16) * 8 + srow;
        gload_lds16(Bt + (size_t)(n0 + row) * K + k0 + scol, (char*)Bs + (chunk - 16) * 1024);
      }
    }
    __syncthreads();
    #pragma unroll
    for (int kk = 0; kk < 2; ++kk) {
      bf16x8 af[4], bfr[2];
      #pragma unroll
      for (int i = 0; i < 4; ++i)
        af[i] = *reinterpret_cast<const bf16x8*>(&As[(wr*64 + i*16 + lr) * 64 + kk*32 + lk]);
      #pragma unroll
      for (int i = 0; i < 2; ++i)
        bfr[i] = *reinterpret_cast<const bf16x8*>(&Bs[(wc*32 + i*16 + lr) * 64 + kk*32 + lk]);
      #pragma unroll
      for (int mi = 0; mi < 4; ++mi)
        #pragma unroll
        for (int ni = 0; ni < 2; ++ni)
          acc[mi][ni] = __builtin_amdgcn_mfma_f32_16x16x32_bf16(af[mi], bfr[ni], acc[mi][ni], 0, 0, 0);
    }
  }

  const float beta = (EPI == 0) ? sigmoidf_(log_beta[0]) : 0.f;
  #pragma unroll
  for (int mi = 0; mi < 4; ++mi)
    #pragma unroll
    for (int ni = 0; ni < 2; ++ni)
      #pragma unroll
      for (int reg = 0; reg < 4; ++reg) {
        const int r = m0 + wr*64 + mi*16 + (lane >> 4) * 4 + reg;
        const int c = n0 + wc*32 + ni*16 + (lane & 15);
        const size_t off = (size_t)r * N + c;
        float v = acc[mi][ni][reg];
        if (EPI == 0) {
          float vel = beta * vin[off] + v;
          float x1  = xin[off] + vel;
          outv[off] = vel;
          C[off] = x1;
        } else {
          C[off] += v;
        }
      }
}

// ---------------- causal depthwise conv (K=3) * silu(g), bf16x8 vectorized ----------------
__global__ __launch_bounds__(256) void conv_gate_kernel(
    const bf16* __restrict__ g1, const float* __restrict__ dw, bf16* __restrict__ mixin)
{
  const int idx = blockIdx.x * 256 + threadIdx.x;   // < BT*DCONV/8
  const int c8 = (idx % (DCONV / 8)) * 8;
  const int bt = idx / (DCONV / 8);
  const int t  = bt & (TSEQ - 1);
  const bf16* row = g1 + (size_t)bt * NG1;

  bf16x8 u2v = *reinterpret_cast<const bf16x8*>(row + c8);
  bf16x8 gv  = *reinterpret_cast<const bf16x8*>(row + DCONV + c8);
  bf16x8 u1v = u2v, u0v = u2v;
  const bool h1 = (t >= 1), h2 = (t >= 2);
  if (h1) u1v = *reinterpret_cast<const bf16x8*>(row - NG1 + c8);
  if (h2) u0v = *reinterpret_cast<const bf16x8*>(row - 2 * NG1 + c8);

  bf16x8 outv;
  #pragma unroll
  for (int j = 0; j < 8; ++j) {
    const int c = c8 + j;
    float u2 = (float)u2v[j];
    float u1 = h1 ? (float)u1v[j] : 0.f;
    float u0 = h2 ? (float)u0v[j] : 0.f;
    float conv = u0 * dw[c*3] + u1 * dw[c*3 + 1] + u2 * dw[c*3 + 2];
    float g = (float)gv[j];
    outv[j] = (bf16)(conv * (g * sigmoidf_(g)));
  }
  *reinterpret_cast<bf16x8*>(mixin + (size_t)bt * DMOD + c8) = outv;
}

// ---------------- RG-LRU 2-pass chunked scan (bf16 inputs) ----------------
#define NCH  32
#define CLEN 64   // TSEQ / NCH

__device__ __forceinline__ void lru_step(const bf16* row, int c, float coef,
                                         float& a, float& g)
{
  float v  = (float)row[2*DCONV + c];
  float r  = sigmoidf_((float)row[2*DCONV + DGRIF + c]);
  float is = sigmoidf_((float)row[2*DCONV + 2*DGRIF + c]);
  float la = coef * r;
  a = __expf(la);
  g = sqrtf(fmaxf(1.f - __expf(2.f * la), EPS_)) * (is * v);
}

__global__ __launch_bounds__(256) void lru_pass1(
    const bf16* __restrict__ g1, const float* __restrict__ lam,
    float* __restrict__ cA, float* __restrict__ cB)
{
  const int idx = blockIdx.x * 256 + threadIdx.x;   // < BSZ*NCH*DGRIF
  const int c = idx % DGRIF;
  const int rest = idx / DGRIF;
  const int j = rest & (NCH - 1);
  const int b = rest / NCH;
  const float coef = -8.f * log1pf(__expf(lam[c]));
  const bf16* base = g1 + (size_t)(b * TSEQ + j * CLEN) * NG1;
  float A = 1.f, Bv = 0.f;
  #pragma unroll 4
  for (int t = 0; t < CLEN; ++t) {
    float a, g;
    lru_step(base + (size_t)t * NG1, c, coef, a, g);
    A *= a;
    Bv = a * Bv + g;
  }
  cA[((size_t)b * DGRIF + c) * NCH + j] = A;
  cB[((size_t)b * DGRIF + c) * NCH + j] = Bv;
}

__global__ __launch_bounds__(256) void lru_pass2(
    const bf16* __restrict__ g1, const float* __restrict__ lam,
    const float* __restrict__ cA, const float* __restrict__ cB,
    bf16* __restrict__ mixin)
{
  const int idx = blockIdx.x * 256 + threadIdx.x;
  const int c = idx % DGRIF;
  const int rest = idx / DGRIF;
  const int j = rest & (NCH - 1);
  const int b = rest / NCH;
  const float coef = -8.f * log1pf(__expf(lam[c]));
  float Hc = 0.f;
  const float* pa = cA + ((size_t)b * DGRIF + c) * NCH;
  const float* pb = cB + ((size_t)b * DGRIF + c) * NCH;
  for (int k = 0; k < j; ++k) Hc = pa[k] * Hc + pb[k];
  const bf16* base = g1 + (size_t)(b * TSEQ + j * CLEN) * NG1;
  bf16* mbase = mixin + (size_t)(b * TSEQ + j * CLEN) * DMOD + DCONV + c;
  #pragma unroll 4
  for (int t = 0; t < CLEN; ++t) {
    float a, g;
    lru_step(base + (size_t)t * NG1, c, coef, a, g);
    Hc = a * Hc + g;
    mbase[(size_t)t * DMOD] = (bf16)Hc;
  }
}

// ---------------- launcher ----------------
extern "C" void kernel_launch(void* const* d_in, const int* in_sizes, int n_in,
                              void* d_out, int out_size, void* d_ws, size_t ws_size,
                              hipStream_t stream)
{
  const float* x         = (const float*)d_in[0];
  const float* vel_in    = (const float*)d_in[1];
  const float* pre_w     = (const float*)d_in[2];
  const float* conv_in_w = (const float*)d_in[3];
  const float* conv_dw   = (const float*)d_in[4];
  const float* gv        = (const float*)d_in[5];
  const float* gr        = (const float*)d_in[6];
  const float* gi        = (const float*)d_in[7];
  const float* lam       = (const float*)d_in[8];
  const float* out_w     = (const float*)d_in[9];
  const float* log_beta  = (const float*)d_in[10];
  const float* ffn_w     = (const float*)d_in[11];
  const float* w1        = (const float*)d_in[12];
  const float* w3        = (const float*)d_in[13];
  const float* w2        = (const float*)d_in[14];

  char* ws = (char*)d_ws;
  size_t off = 0;
  auto alloc = [&](size_t bytes) { void* p = ws + off; off += (bytes + 255) & ~(size_t)255; return p; };

  bf16*  WT_G1  = (bf16*)alloc((size_t)NG1 * DMOD * 2);          // [1920][768]
  bf16*  WT_OUT = (bf16*)alloc((size_t)DMOD * DMOD * 2);         // [768][768]
  bf16*  WT_W13 = (bf16*)alloc((size_t)2 * DFFN * DMOD * 2);     // [4096][768] interleaved
  bf16*  WT_W2  = (bf16*)alloc((size_t)DMOD * DFFN * 2);         // [768][2048]
  float* CA     = (float*)alloc((size_t)BSZ * DGRIF * NCH * 4);
  float* CB     = (float*)alloc((size_t)BSZ * DGRIF * NCH * 4);
  bf16*  XN     = (bf16*)alloc((size_t)BT * DMOD * 2);           // 12.6 MB
  bf16*  G1     = (bf16*)alloc((size_t)BT * NG1 * 2);            // 31.5 MB
  bf16*  MIXIN  = (bf16*)alloc((size_t)BT * DMOD * 2);           // 12.6 MB
  bf16*  H      = (bf16*)alloc((size_t)BT * DFFN * 2);           // 33.6 MB
  bf16*  NORMED = (bf16*)alloc((size_t)BT * DMOD * 2);           // 12.6 MB

  float* OUTX   = (float*)d_out;
  float* OUTV   = OUTX + (size_t)BT * DMOD;

  const dim3 tb(32, 8);
  // weight transposes -> bf16 [N][K]
  transpose_bf16_kernel<0><<<dim3(DMOD/32,  DMOD/32), tb, 0, stream>>>(conv_in_w, WT_G1, DMOD, DMOD, 0);
  transpose_bf16_kernel<0><<<dim3(DGRIF/32, DMOD/32), tb, 0, stream>>>(gv, WT_G1 + (size_t)(2*DCONV) * DMOD, DMOD, DGRIF, 0);
  transpose_bf16_kernel<0><<<dim3(DGRIF/32, DMOD/32), tb, 0, stream>>>(gr, WT_G1 + (size_t)(2*DCONV + DGRIF) * DMOD, DMOD, DGRIF, 0);
  transpose_bf16_kernel<0><<<dim3(DGRIF/32, DMOD/32), tb, 0, stream>>>(gi, WT_G1 + (size_t)(2*DCONV + 2*DGRIF) * DMOD, DMOD, DGRIF, 0);
  transpose_bf16_kernel<0><<<dim3(DMOD/32,  DMOD/32), tb, 0, stream>>>(out_w, WT_OUT, DMOD, DMOD, 0);
  transpose_bf16_kernel<1><<<dim3(DFFN/32,  DMOD/32), tb, 0, stream>>>(w1, WT_W13, DMOD, DFFN, 0);
  transpose_bf16_kernel<1><<<dim3(DFFN/32,  DMOD/32), tb, 0, stream>>>(w3, WT_W13, DMOD, DFFN, 64);
  transpose_bf16_kernel<0><<<dim3(DMOD/32,  DFFN/32), tb, 0, stream>>>(w2, WT_W2, DFFN, DMOD, 0);

  // pre-norm
  rmsnorm_kernel<<<BT, 256, 0, stream>>>(x, pre_w, XN);

  // GEMM1: [8192,768] @ [768,1920] -> G1 (bf16)
  gemm_w128<<<(NG1/128) * (BT/128), 256, 0, stream>>>(XN, WT_G1, G1, BT, NG1, DMOD, NG1/128);

  // conv branch + RG-LRU branch -> MIXIN
  conv_gate_kernel<<<(BT * DCONV / 8) / 256, 256, 0, stream>>>(G1, conv_dw, MIXIN);
  lru_pass1<<<(BSZ * NCH * DGRIF) / 256, 256, 0, stream>>>(G1, lam, CA, CB);
  lru_pass2<<<(BSZ * NCH * DGRIF) / 256, 256, 0, stream>>>(G1, lam, CA, CB, MIXIN);

  // GEMM2 + momentum epilogue: OUTX = x + vel, OUTV = vel
  gemm_n64<0><<<(DMOD/64) * (BT/128), 256, 0, stream>>>(MIXIN, WT_OUT, OUTX, x, vel_in, OUTV,
                                                        log_beta, BT, DMOD, DMOD, DMOD/64);

  // ffn rmsnorm on x1
  rmsnorm_kernel<<<BT, 256, 0, stream>>>(OUTX, ffn_w, NORMED);

  // fused FFN up-proj + SwiGLU gate -> H (bf16)
  gemm_ffn13<<<(DFFN/64) * (BT/128), 256, 0, stream>>>(NORMED, WT_W13, H, BT, DMOD, DFFN/64);

  // down-proj, accumulate into OUTX
  gemm_n64<1><<<(DMOD/64) * (BT/128), 256, 0, stream>>>(H, WT_W2, OUTX, nullptr, nullptr, nullptr,
                                                        nullptr, BT, DMOD, DFFN, DMOD/64);
}

// Round 4
// 320.447 us; speedup vs baseline: 1.0943x; 1.0091x over previous
//
#include <hip/hip_runtime.h>
#include <hip/hip_bf16.h>
#include <cstdint>

// ---------------- problem constants ----------------
#define BSZ   4
#define TSEQ  2048
#define DMOD  768
#define DCONV 384
#define DGRIF 384
#define DFFN  2048
#define BT    (BSZ*TSEQ)          // 8192
#define NG1   1920                // 2*DCONV + 3*DGRIF
#define EPS_  1e-6f

typedef __bf16 bf16;
typedef __bf16 bf16x8 __attribute__((ext_vector_type(8)));
typedef float  f32x4  __attribute__((ext_vector_type(4)));

__device__ __forceinline__ float sigmoidf_(float x) { return 1.f / (1.f + __expf(-x)); }

// async global->LDS, 16B per lane; LDS dest must be wave-uniform base
__device__ __forceinline__ void gload_lds16(const void* g, void* l) {
  __builtin_amdgcn_global_load_lds(
      (const __attribute__((address_space(1))) void*)(uintptr_t)g,
      (__attribute__((address_space(3))) void*)(uint32_t)(uintptr_t)l,
      16, 0, 0);
}

// bijective XCD swizzle: nwg % 8 == 0 for all our grids
__device__ __forceinline__ int swz_wg() {
  const int nwg = gridDim.x;
  const int bid = blockIdx.x;
  const int cpx = nwg >> 3;
  return (bid & 7) * cpx + (bid >> 3);
}

// ---------------- weight transpose + bf16 cast ----------------
// W: [R][C] fp32  ->  Wt[out_row][R] bf16.  MODE 0: out_row = c.
// MODE 1: out_row = (c/64)*128 + half + (c%64)   (w1/w3 interleave for fused FFN)
template <int MODE>
__global__ __launch_bounds__(256) void transpose_bf16_kernel(
    const float* __restrict__ W, bf16* __restrict__ Wt, int R, int C, int half)
{
  __shared__ float tile[32][33];
  const int tc = blockIdx.x * 32;   // input col tile
  const int tr = blockIdx.y * 32;   // input row tile
  const int lx = threadIdx.x;       // 0..31
  const int ly = threadIdx.y;       // 0..7
  #pragma unroll
  for (int i = ly; i < 32; i += 8) {
    int r = tr + i, c = tc + lx;
    tile[i][lx] = (r < R && c < C) ? W[(size_t)r * C + c] : 0.f;
  }
  __syncthreads();
  #pragma unroll
  for (int i = ly; i < 32; i += 8) {
    int oc = tc + i;    // input col
    int orr = tr + lx;  // input row -> output col
    if (oc < C && orr < R) {
      int orow = (MODE == 0) ? oc : ((oc >> 6) << 7) + half + (oc & 63);
      Wt[(size_t)orow * R + orr] = (bf16)tile[lx][i];
    }
  }
}

// ---------------- rmsnorm (x fp32 -> out bf16) ----------------
__global__ __launch_bounds__(256) void rmsnorm_kernel(
    const float* __restrict__ x, const float* __restrict__ w, bf16* __restrict__ out)
{
  __shared__ float sbuf[4];
  const int row = blockIdx.x;
  const int tid = threadIdx.x;
  const float* xr = x + (size_t)row * DMOD;
  float v0 = xr[tid], v1 = xr[tid + 256], v2 = xr[tid + 512];
  float s = v0*v0 + v1*v1 + v2*v2;
  #pragma unroll
  for (int o = 32; o > 0; o >>= 1) s += __shfl_down(s, o, 64);
  if ((tid & 63) == 0) sbuf[tid >> 6] = s;
  __syncthreads();
  float tot = sbuf[0] + sbuf[1] + sbuf[2] + sbuf[3];
  float rms = rsqrtf(tot * (1.f / (float)DMOD) + EPS_);
  bf16* orow = out + (size_t)row * DMOD;
  orow[tid]       = (bf16)(v0 * rms * w[tid]);
  orow[tid + 256] = (bf16)(v1 * rms * w[tid + 256]);
  orow[tid + 512] = (bf16)(v2 * rms * w[tid + 512]);
}

// ---------------- wide GEMM: 128x128 tile, bf16 C out (GEMM1) ----------------
__global__ __launch_bounds__(256) void gemm_w128(
    const bf16* __restrict__ A, const bf16* __restrict__ Bt, bf16* __restrict__ C,
    int M, int N, int K, int nx)
{
  __shared__ alignas(16) unsigned short As[128 * 64];
  __shared__ alignas(16) unsigned short Bs[128 * 64];

  const int wg = swz_wg();
  const int m0 = (wg / nx) * 128, n0 = (wg % nx) * 128;
  const int tid  = threadIdx.x;
  const int wave = tid >> 6;
  const int lane = tid & 63;
  const int wr = wave >> 1, wc = wave & 1;

  f32x4 acc[4][4] = {};
  const int srow = lane >> 3;
  const int scol = (lane & 7) * 8;
  const int lr = lane & 15;
  const int lk = (lane >> 4) * 8;

  for (int k0 = 0; k0 < K; k0 += 64) {
    __syncthreads();
    #pragma unroll
    for (int it = 0; it < 4; ++it) {
      const int chunk = wave * 4 + it;
      const int row = chunk * 8 + srow;
      gload_lds16(A  + (size_t)(m0 + row) * K + k0 + scol, (char*)As + chunk * 1024);
      gload_lds16(Bt + (size_t)(n0 + row) * K + k0 + scol, (char*)Bs + chunk * 1024);
    }
    __syncthreads();
    #pragma unroll
    for (int kk = 0; kk < 2; ++kk) {
      bf16x8 af[4], bfr[4];
      #pragma unroll
      for (int i = 0; i < 4; ++i)
        af[i] = *reinterpret_cast<const bf16x8*>(&As[(wr*64 + i*16 + lr) * 64 + kk*32 + lk]);
      #pragma unroll
      for (int i = 0; i < 4; ++i)
        bfr[i] = *reinterpret_cast<const bf16x8*>(&Bs[(wc*64 + i*16 + lr) * 64 + kk*32 + lk]);
      #pragma unroll
      for (int mi = 0; mi < 4; ++mi)
        #pragma unroll
        for (int ni = 0; ni < 4; ++ni)
          acc[mi][ni] = __builtin_amdgcn_mfma_f32_16x16x32_bf16(af[mi], bfr[ni], acc[mi][ni], 0, 0, 0);
    }
  }

  #pragma unroll
  for (int mi = 0; mi < 4; ++mi)
    #pragma unroll
    for (int ni = 0; ni < 4; ++ni)
      #pragma unroll
      for (int reg = 0; reg < 4; ++reg) {
        const int r = m0 + wr*64 + mi*16 + (lane >> 4) * 4 + reg;
        const int c = n0 + wc*64 + ni*16 + (lane & 15);
        C[(size_t)r * N + c] = (bf16)acc[mi][ni][reg];
      }
}

// ---------------- fused FFN GEMM: p1|p3 interleaved, epilogue silu(p1)*p3 ----------------
// Bt: [2*DFFN][K] with rows (j*128 + 0..63) = w1 cols j*64.., rows (j*128+64..127) = w3.
// comb (p3 pass-through) aliases As: As is dead after the K-loop. LDS stays 32 KB.
__global__ __launch_bounds__(256) void gemm_ffn13(
    const bf16* __restrict__ A, const bf16* __restrict__ Bt, bf16* __restrict__ H,
    int M, int K, int nx)   // nx = DFFN/64 = 32
{
  __shared__ alignas(16) unsigned short As[128 * 64];
  __shared__ alignas(16) unsigned short Bs[128 * 64];
  bf16* comb = reinterpret_cast<bf16*>(As);   // reuse As for p3 pass-through

  const int wg = swz_wg();
  const int m0 = (wg / nx) * 128;
  const int bx = wg % nx;
  const int n0 = bx * 128;            // row base into Bt
  const int tid  = threadIdx.x;
  const int wave = tid >> 6;
  const int lane = tid & 63;
  const int wr = wave >> 1, wc = wave & 1;

  f32x4 acc[4][4] = {};
  const int srow = lane >> 3;
  const int scol = (lane & 7) * 8;
  const int lr = lane & 15;
  const int lk = (lane >> 4) * 8;

  for (int k0 = 0; k0 < K; k0 += 64) {
    __syncthreads();
    #pragma unroll
    for (int it = 0; it < 4; ++it) {
      const int chunk = wave * 4 + it;
      const int row = chunk * 8 + srow;
      gload_lds16(A  + (size_t)(m0 + row) * K + k0 + scol, (char*)As + chunk * 1024);
      gload_lds16(Bt + (size_t)(n0 + row) * K + k0 + scol, (char*)Bs + chunk * 1024);
    }
    __syncthreads();
    #pragma unroll
    for (int kk = 0; kk < 2; ++kk) {
      bf16x8 af[4], bfr[4];
      #pragma unroll
      for (int i = 0; i < 4; ++i)
        af[i] = *reinterpret_cast<const bf16x8*>(&As[(wr*64 + i*16 + lr) * 64 + kk*32 + lk]);
      #pragma unroll
      for (int i = 0; i < 4; ++i)
        bfr[i] = *reinterpret_cast<const bf16x8*>(&Bs[(wc*64 + i*16 + lr) * 64 + kk*32 + lk]);
      #pragma unroll
      for (int mi = 0; mi < 4; ++mi)
        #pragma unroll
        for (int ni = 0; ni < 4; ++ni)
          acc[mi][ni] = __builtin_amdgcn_mfma_f32_16x16x32_bf16(af[mi], bfr[ni], acc[mi][ni], 0, 0, 0);
    }
  }

  __syncthreads();   // all waves done with As before overwriting it as comb
  // wc==1 waves hold p3 (w3 half); stash through LDS, wc==0 waves emit gated H
  if (wc == 1) {
    #pragma unroll
    for (int mi = 0; mi < 4; ++mi)
      #pragma unroll
      for (int ni = 0; ni < 4; ++ni)
        #pragma unroll
        for (int reg = 0; reg < 4; ++reg) {
          const int row = wr*64 + mi*16 + (lane >> 4) * 4 + reg;
          const int col = ni*16 + (lane & 15);
          comb[row * 64 + col] = (bf16)acc[mi][ni][reg];
        }
  }
  __syncthreads();
  if (wc == 0) {
    #pragma unroll
    for (int mi = 0; mi < 4; ++mi)
      #pragma unroll
      for (int ni = 0; ni < 4; ++ni)
        #pragma unroll
        for (int reg = 0; reg < 4; ++reg) {
          const int row = wr*64 + mi*16 + (lane >> 4) * 4 + reg;
          const int col = ni*16 + (lane & 15);
          float p3 = (float)comb[row * 64 + col];
          float p1 = acc[mi][ni][reg];
          H[(size_t)(m0 + row) * DFFN + bx * 64 + col] = (bf16)(p1 * sigmoidf_(p1) * p3);
        }
  }
}

// ---------------- narrow GEMM: 128x64 tile (N=768 GEMMs) ----------------
// EPI 0: momentum epilogue (vel = beta*vin + acc; x1 = x + vel -> outx, outv)
// EPI 1: C += acc (residual accumulate)
template <int EPI>
__global__ __launch_bounds__(256) void gemm_n64(
    const bf16* __restrict__ A, const bf16* __restrict__ Bt, float* __restrict__ C,
    const float* __restrict__ xin, const float* __restrict__ vin,
    float* __restrict__ outv, const float* __restrict__ log_beta,
    int M, int N, int K, int nx)
{
  __shared__ alignas(16) unsigned short As[128 * 64];   // 16 KB
  __shared__ alignas(16) unsigned short Bs[64 * 64];    //  8 KB

  const int wg = swz_wg();
  const int m0 = (wg / nx) * 128, n0 = (wg % nx) * 64;
  const int tid  = threadIdx.x;
  const int wave = tid >> 6;
  const int lane = tid & 63;
  const int wr = wave >> 1, wc = wave & 1;   // wave tile: 64 rows x 32 cols

  f32x4 acc[4][2] = {};
  const int srow = lane >> 3;
  const int scol = (lane & 7) * 8;
  const int lr = lane & 15;
  const int lk = (lane >> 4) * 8;

  for (int k0 = 0; k0 < K; k0 += 64) {
    __syncthreads();
    #pragma unroll
    for (int it = 0; it < 6; ++it) {
      const int chunk = wave * 6 + it;      // 0..23: 16 A-chunks then 8 B-chunks
      if (chunk < 16) {
        const int row = chunk * 8 + srow;
        gload_lds16(A + (size_t)(m0 + row) * K + k0 + scol, (char*)As + chunk * 1024);
      } else {
        const int row = (chunk - 16) * 8 + srow;
        gload_lds16(Bt + (size_t)(n0 + row) * K + k0 + scol, (char*)Bs + (chunk - 16) * 1024);
      }
    }
    __syncthreads();
    #pragma unroll
    for (int kk = 0; kk < 2; ++kk) {
      bf16x8 af[4], bfr[2];
      #pragma unroll
      for (int i = 0; i < 4; ++i)
        af[i] = *reinterpret_cast<const bf16x8*>(&As[(wr*64 + i*16 + lr) * 64 + kk*32 + lk]);
      #pragma unroll
      for (int i = 0; i < 2; ++i)
        bfr[i] = *reinterpret_cast<const bf16x8*>(&Bs[(wc*32 + i*16 + lr) * 64 + kk*32 + lk]);
      #pragma unroll
      for (int mi = 0; mi < 4; ++mi)
        #pragma unroll
        for (int ni = 0; ni < 2; ++ni)
          acc[mi][ni] = __builtin_amdgcn_mfma_f32_16x16x32_bf16(af[mi], bfr[ni], acc[mi][ni], 0, 0, 0);
    }
  }

  const float beta = (EPI == 0) ? sigmoidf_(log_beta[0]) : 0.f;
  #pragma unroll
  for (int mi = 0; mi < 4; ++mi)
    #pragma unroll
    for (int ni = 0; ni < 2; ++ni)
      #pragma unroll
      for (int reg = 0; reg < 4; ++reg) {
        const int r = m0 + wr*64 + mi*16 + (lane >> 4) * 4 + reg;
        const int c = n0 + wc*32 + ni*16 + (lane & 15);
        const size_t off = (size_t)r * N + c;
        float v = acc[mi][ni][reg];
        if (EPI == 0) {
          float vel = beta * vin[off] + v;
          float x1  = xin[off] + vel;
          outv[off] = vel;
          C[off] = x1;
        } else {
          C[off] += v;
        }
      }
}

// ---------------- RG-LRU 2-pass chunked scan (bf16 inputs) ----------------
#define NCH  32
#define CLEN 64   // TSEQ / NCH

__device__ __forceinline__ void lru_step(const bf16* row, int c, float coef,
                                         float& a, float& g)
{
  float v  = (float)row[2*DCONV + c];
  float r  = sigmoidf_((float)row[2*DCONV + DGRIF + c]);
  float is = sigmoidf_((float)row[2*DCONV + 2*DGRIF + c]);
  float la = coef * r;
  a = __expf(la);
  g = sqrtf(fmaxf(1.f - __expf(2.f * la), EPS_)) * (is * v);
}

__global__ __launch_bounds__(256) void lru_pass1(
    const bf16* __restrict__ g1, const float* __restrict__ lam,
    float* __restrict__ cA, float* __restrict__ cB)
{
  const int idx = blockIdx.x * 256 + threadIdx.x;   // < BSZ*NCH*DGRIF
  const int c = idx % DGRIF;
  const int rest = idx / DGRIF;
  const int j = rest & (NCH - 1);
  const int b = rest / NCH;
  const float coef = -8.f * log1pf(__expf(lam[c]));
  const bf16* base = g1 + (size_t)(b * TSEQ + j * CLEN) * NG1;
  float A = 1.f, Bv = 0.f;
  #pragma unroll 4
  for (int t = 0; t < CLEN; ++t) {
    float a, g;
    lru_step(base + (size_t)t * NG1, c, coef, a, g);
    A *= a;
    Bv = a * Bv + g;
  }
  cA[((size_t)b * DGRIF + c) * NCH + j] = A;
  cB[((size_t)b * DGRIF + c) * NCH + j] = Bv;
}

// pass2 also does the causal depthwise conv (K=3) * silu(g) for channel c:
// same (b, chunk, c) decomposition, walks t sequentially with a sliding window.
__global__ __launch_bounds__(256) void lru_pass2(
    const bf16* __restrict__ g1, const float* __restrict__ lam,
    const float* __restrict__ cA, const float* __restrict__ cB,
    const float* __restrict__ dw, bf16* __restrict__ mixin)
{
  const int idx = blockIdx.x * 256 + threadIdx.x;
  const int c = idx % DGRIF;
  const int rest = idx / DGRIF;
  const int j = rest & (NCH - 1);
  const int b = rest / NCH;
  const float coef = -8.f * log1pf(__expf(lam[c]));
  // lru carry from preceding chunks
  float Hc = 0.f;
  const float* pa = cA + ((size_t)b * DGRIF + c) * NCH;
  const float* pb = cB + ((size_t)b * DGRIF + c) * NCH;
  for (int k = 0; k < j; ++k) Hc = pa[k] * Hc + pb[k];

  const int t0 = j * CLEN;
  const bf16* base = g1 + (size_t)(b * TSEQ + t0) * NG1;
  // conv sliding-window lookback
  const float w0 = dw[c*3], w1 = dw[c*3 + 1], w2 = dw[c*3 + 2];
  float u1 = (t0 >= 1) ? (float)base[-(ptrdiff_t)NG1 + c]     : 0.f;
  float u0 = (t0 >= 2) ? (float)base[-(ptrdiff_t)(2*NG1) + c] : 0.f;

  bf16* mbase = mixin + (size_t)(b * TSEQ + t0) * DMOD;
  #pragma unroll 4
  for (int t = 0; t < CLEN; ++t) {
    const bf16* row = base + (size_t)t * NG1;
    // conv branch
    float u2 = (float)row[c];
    float gg = (float)row[DCONV + c];
    float conv = u0 * w0 + u1 * w1 + u2 * w2;
    mbase[(size_t)t * DMOD + c] = (bf16)(conv * (gg * sigmoidf_(gg)));
    u0 = u1; u1 = u2;
    // lru branch
    float a, g;
    lru_step(row, c, coef, a, g);
    Hc = a * Hc + g;
    mbase[(size_t)t * DMOD + DCONV + c] = (bf16)Hc;
  }
}

// ---------------- launcher ----------------
extern "C" void kernel_launch(void* const* d_in, const int* in_sizes, int n_in,
                              void* d_out, int out_size, void* d_ws, size_t ws_size,
                              hipStream_t stream)
{
  const float* x         = (const float*)d_in[0];
  const float* vel_in    = (const float*)d_in[1];
  const float* pre_w     = (const float*)d_in[2];
  const float* conv_in_w = (const float*)d_in[3];
  const float* conv_dw   = (const float*)d_in[4];
  const float* gv        = (const float*)d_in[5];
  const float* gr        = (const float*)d_in[6];
  const float* gi        = (const float*)d_in[7];
  const float* lam       = (const float*)d_in[8];
  const float* out_w     = (const float*)d_in[9];
  const float* log_beta  = (const float*)d_in[10];
  const float* ffn_w     = (const float*)d_in[11];
  const float* w1        = (const float*)d_in[12];
  const float* w3        = (const float*)d_in[13];
  const float* w2        = (const float*)d_in[14];

  char* ws = (char*)d_ws;
  size_t off = 0;
  auto alloc = [&](size_t bytes) { void* p = ws + off; off += (bytes + 255) & ~(size_t)255; return p; };

  bf16*  WT_G1  = (bf16*)alloc((size_t)NG1 * DMOD * 2);          // [1920][768]
  bf16*  WT_OUT = (bf16*)alloc((size_t)DMOD * DMOD * 2);         // [768][768]
  bf16*  WT_W13 = (bf16*)alloc((size_t)2 * DFFN * DMOD * 2);     // [4096][768] interleaved
  bf16*  WT_W2  = (bf16*)alloc((size_t)DMOD * DFFN * 2);         // [768][2048]
  float* CA     = (float*)alloc((size_t)BSZ * DGRIF * NCH * 4);
  float* CB     = (float*)alloc((size_t)BSZ * DGRIF * NCH * 4);
  bf16*  XN     = (bf16*)alloc((size_t)BT * DMOD * 2);           // 12.6 MB
  bf16*  G1     = (bf16*)alloc((size_t)BT * NG1 * 2);            // 31.5 MB
  bf16*  MIXIN  = (bf16*)alloc((size_t)BT * DMOD * 2);           // 12.6 MB
  bf16*  H      = (bf16*)alloc((size_t)BT * DFFN * 2);           // 33.6 MB
  bf16*  NORMED = (bf16*)alloc((size_t)BT * DMOD * 2);           // 12.6 MB

  float* OUTX   = (float*)d_out;
  float* OUTV   = OUTX + (size_t)BT * DMOD;

  const dim3 tb(32, 8);
  // weight transposes -> bf16 [N][K]
  transpose_bf16_kernel<0><<<dim3(DMOD/32,  DMOD/32), tb, 0, stream>>>(conv_in_w, WT_G1, DMOD, DMOD, 0);
  transpose_bf16_kernel<0><<<dim3(DGRIF/32, DMOD/32), tb, 0, stream>>>(gv, WT_G1 + (size_t)(2*DCONV) * DMOD, DMOD, DGRIF, 0);
  transpose_bf16_kernel<0><<<dim3(DGRIF/32, DMOD/32), tb, 0, stream>>>(gr, WT_G1 + (size_t)(2*DCONV + DGRIF) * DMOD, DMOD, DGRIF, 0);
  transpose_bf16_kernel<0><<<dim3(DGRIF/32, DMOD/32), tb, 0, stream>>>(gi, WT_G1 + (size_t)(2*DCONV + 2*DGRIF) * DMOD, DMOD, DGRIF, 0);
  transpose_bf16_kernel<0><<<dim3(DMOD/32,  DMOD/32), tb, 0, stream>>>(out_w, WT_OUT, DMOD, DMOD, 0);
  transpose_bf16_kernel<1><<<dim3(DFFN/32,  DMOD/32), tb, 0, stream>>>(w1, WT_W13, DMOD, DFFN, 0);
  transpose_bf16_kernel<1><<<dim3(DFFN/32,  DMOD/32), tb, 0, stream>>>(w3, WT_W13, DMOD, DFFN, 64);
  transpose_bf16_kernel<0><<<dim3(DMOD/32,  DFFN/32), tb, 0, stream>>>(w2, WT_W2, DFFN, DMOD, 0);

  // pre-norm
  rmsnorm_kernel<<<BT, 256, 0, stream>>>(x, pre_w, XN);

  // GEMM1: [8192,768] @ [768,1920] -> G1 (bf16)
  gemm_w128<<<(NG1/128) * (BT/128), 256, 0, stream>>>(XN, WT_G1, G1, BT, NG1, DMOD, NG1/128);

  // RG-LRU branch + fused conv branch -> MIXIN
  lru_pass1<<<(BSZ * NCH * DGRIF) / 256, 256, 0, stream>>>(G1, lam, CA, CB);
  lru_pass2<<<(BSZ * NCH * DGRIF) / 256, 256, 0, stream>>>(G1, lam, CA, CB, conv_dw, MIXIN);

  // GEMM2 + momentum epilogue: OUTX = x + vel, OUTV = vel
  gemm_n64<0><<<(DMOD/64) * (BT/128), 256, 0, stream>>>(MIXIN, WT_OUT, OUTX, x, vel_in, OUTV,
                                                        log_beta, BT, DMOD, DMOD, DMOD/64);

  // ffn rmsnorm on x1
  rmsnorm_kernel<<<BT, 256, 0, stream>>>(OUTX, ffn_w, NORMED);

  // fused FFN up-proj + SwiGLU gate -> H (bf16)
  gemm_ffn13<<<(DFFN/64) * (BT/128), 256, 0, stream>>>(NORMED, WT_W13, H, BT, DMOD, DFFN/64);

  // down-proj, accumulate into OUTX
  gemm_n64<1><<<(DMOD/64) * (BT/128), 256, 0, stream>>>(H, WT_W2, OUTX, nullptr, nullptr, nullptr,
                                                        nullptr, BT, DMOD, DFFN, DMOD/64);
}

// Round 5
// 287.107 us; speedup vs baseline: 1.2213x; 1.1161x over previous
//
#include <hip/hip_runtime.h>
#include <hip/hip_bf16.h>
#include <cstdint>

// ---------------- problem constants ----------------
#define BSZ   4
#define TSEQ  2048
#define DMOD  768
#define DCONV 384
#define DGRIF 384
#define DFFN  2048
#define BT    (BSZ*TSEQ)          // 8192
#define NG1   1920                // 2*DCONV + 3*DGRIF
#define EPS_  1e-6f

typedef __bf16 bf16;
typedef __bf16 bf16x8 __attribute__((ext_vector_type(8)));
typedef float  f32x4  __attribute__((ext_vector_type(4)));

__device__ __forceinline__ float sigmoidf_(float x) { return 1.f / (1.f + __expf(-x)); }

// async global->LDS, 16B per lane; LDS dest must be wave-uniform base
__device__ __forceinline__ void gload_lds16(const void* g, void* l) {
  __builtin_amdgcn_global_load_lds(
      (const __attribute__((address_space(1))) void*)(uintptr_t)g,
      (__attribute__((address_space(3))) void*)(uint32_t)(uintptr_t)l,
      16, 0, 0);
}

// bijective XCD swizzle: nwg % 8 == 0 for all our grids
__device__ __forceinline__ int swz_wg() {
  const int nwg = gridDim.x;
  const int bid = blockIdx.x;
  const int cpx = nwg >> 3;
  return (bid & 7) * cpx + (bid >> 3);
}

// LDS T2 swizzle: tile row stride = 64 bf16 = 128 B = 8 x 16B slots.
// Content at (row, slot s) = global (row, slot s ^ (row&7)).
// Staging: lane's dest slot is (lane&7) at row srow -> load global slot (lane&7)^srow.
// Reading global slot sb of row r -> LDS slot sb ^ (r&7).

// ---------------- weight transpose + bf16 cast ----------------
// W: [R][C] fp32  ->  Wt[out_row][R] bf16.  MODE 0: out_row = c.
// MODE 1: out_row = (c/64)*128 + half + (c%64)   (w1/w3 interleave for fused FFN)
template <int MODE>
__global__ __launch_bounds__(256) void transpose_bf16_kernel(
    const float* __restrict__ W, bf16* __restrict__ Wt, int R, int C, int half)
{
  __shared__ float tile[32][33];
  const int tc = blockIdx.x * 32;   // input col tile
  const int tr = blockIdx.y * 32;   // input row tile
  const int lx = threadIdx.x;       // 0..31
  const int ly = threadIdx.y;       // 0..7
  #pragma unroll
  for (int i = ly; i < 32; i += 8) {
    int r = tr + i, c = tc + lx;
    tile[i][lx] = (r < R && c < C) ? W[(size_t)r * C + c] : 0.f;
  }
  __syncthreads();
  #pragma unroll
  for (int i = ly; i < 32; i += 8) {
    int oc = tc + i;    // input col
    int orr = tr + lx;  // input row -> output col
    if (oc < C && orr < R) {
      int orow = (MODE == 0) ? oc : ((oc >> 6) << 7) + half + (oc & 63);
      Wt[(size_t)orow * R + orr] = (bf16)tile[lx][i];
    }
  }
}

// ---------------- rmsnorm (x fp32 -> out bf16) ----------------
__global__ __launch_bounds__(256) void rmsnorm_kernel(
    const float* __restrict__ x, const float* __restrict__ w, bf16* __restrict__ out)
{
  __shared__ float sbuf[4];
  const int row = blockIdx.x;
  const int tid = threadIdx.x;
  const float* xr = x + (size_t)row * DMOD;
  float v0 = xr[tid], v1 = xr[tid + 256], v2 = xr[tid + 512];
  float s = v0*v0 + v1*v1 + v2*v2;
  #pragma unroll
  for (int o = 32; o > 0; o >>= 1) s += __shfl_down(s, o, 64);
  if ((tid & 63) == 0) sbuf[tid >> 6] = s;
  __syncthreads();
  float tot = sbuf[0] + sbuf[1] + sbuf[2] + sbuf[3];
  float rms = rsqrtf(tot * (1.f / (float)DMOD) + EPS_);
  bf16* orow = out + (size_t)row * DMOD;
  orow[tid]       = (bf16)(v0 * rms * w[tid]);
  orow[tid + 256] = (bf16)(v1 * rms * w[tid + 256]);
  orow[tid + 512] = (bf16)(v2 * rms * w[tid + 512]);
}

// ---------------- wide GEMM: 128x128 tile, bf16 C out (GEMM1) ----------------
__global__ __launch_bounds__(256) void gemm_w128(
    const bf16* __restrict__ A, const bf16* __restrict__ Bt, bf16* __restrict__ C,
    int M, int N, int K, int nx)
{
  __shared__ alignas(16) unsigned short As[128 * 64];
  __shared__ alignas(16) unsigned short Bs[128 * 64];

  const int wg = swz_wg();
  const int m0 = (wg / nx) * 128, n0 = (wg % nx) * 128;
  const int tid  = threadIdx.x;
  const int wave = tid >> 6;
  const int lane = tid & 63;
  const int wr = wave >> 1, wc = wave & 1;

  f32x4 acc[4][4] = {};
  const int srow = lane >> 3;                   // 0..7 row within chunk
  const int scol = ((lane & 7) ^ srow) * 8;     // pre-swizzled source slot
  const int lr = lane & 15;
  const int lsw = lr & 7;                       // read-side row XOR key
  const int lk4 = lane >> 4;                    // 0..3 k-slot base

  for (int k0 = 0; k0 < K; k0 += 64) {
    __syncthreads();
    #pragma unroll
    for (int it = 0; it < 4; ++it) {
      const int chunk = wave * 4 + it;
      const int row = chunk * 8 + srow;
      gload_lds16(A  + (size_t)(m0 + row) * K + k0 + scol, (char*)As + chunk * 1024);
      gload_lds16(Bt + (size_t)(n0 + row) * K + k0 + scol, (char*)Bs + chunk * 1024);
    }
    __syncthreads();
    #pragma unroll
    for (int kk = 0; kk < 2; ++kk) {
      bf16x8 af[4], bfr[4];
      #pragma unroll
      for (int i = 0; i < 4; ++i)
        af[i] = *reinterpret_cast<const bf16x8*>(
            &As[(wr*64 + i*16 + lr) * 64 + (((kk*4 + lk4) ^ lsw) * 8)]);
      #pragma unroll
      for (int i = 0; i < 4; ++i)
        bfr[i] = *reinterpret_cast<const bf16x8*>(
            &Bs[(wc*64 + i*16 + lr) * 64 + (((kk*4 + lk4) ^ lsw) * 8)]);
      #pragma unroll
      for (int mi = 0; mi < 4; ++mi)
        #pragma unroll
        for (int ni = 0; ni < 4; ++ni)
          acc[mi][ni] = __builtin_amdgcn_mfma_f32_16x16x32_bf16(af[mi], bfr[ni], acc[mi][ni], 0, 0, 0);
    }
  }

  #pragma unroll
  for (int mi = 0; mi < 4; ++mi)
    #pragma unroll
    for (int ni = 0; ni < 4; ++ni)
      #pragma unroll
      for (int reg = 0; reg < 4; ++reg) {
        const int r = m0 + wr*64 + mi*16 + (lane >> 4) * 4 + reg;
        const int c = n0 + wc*64 + ni*16 + (lane & 15);
        C[(size_t)r * N + c] = (bf16)acc[mi][ni][reg];
      }
}

// ---------------- fused FFN GEMM: p1|p3 interleaved, epilogue silu(p1)*p3 ----------------
// Bt: [2*DFFN][K] with rows (j*128 + 0..63) = w1 cols j*64.., rows (j*128+64..127) = w3.
// comb (p3 pass-through) aliases As: As is dead after the K-loop. LDS stays 32 KB.
__global__ __launch_bounds__(256) void gemm_ffn13(
    const bf16* __restrict__ A, const bf16* __restrict__ Bt, bf16* __restrict__ H,
    int M, int K, int nx)   // nx = DFFN/64 = 32
{
  __shared__ alignas(16) unsigned short As[128 * 64];
  __shared__ alignas(16) unsigned short Bs[128 * 64];
  bf16* comb = reinterpret_cast<bf16*>(As);   // reuse As for p3 pass-through

  const int wg = swz_wg();
  const int m0 = (wg / nx) * 128;
  const int bx = wg % nx;
  const int n0 = bx * 128;            // row base into Bt
  const int tid  = threadIdx.x;
  const int wave = tid >> 6;
  const int lane = tid & 63;
  const int wr = wave >> 1, wc = wave & 1;

  f32x4 acc[4][4] = {};
  const int srow = lane >> 3;
  const int scol = ((lane & 7) ^ srow) * 8;
  const int lr = lane & 15;
  const int lsw = lr & 7;
  const int lk4 = lane >> 4;

  for (int k0 = 0; k0 < K; k0 += 64) {
    __syncthreads();
    #pragma unroll
    for (int it = 0; it < 4; ++it) {
      const int chunk = wave * 4 + it;
      const int row = chunk * 8 + srow;
      gload_lds16(A  + (size_t)(m0 + row) * K + k0 + scol, (char*)As + chunk * 1024);
      gload_lds16(Bt + (size_t)(n0 + row) * K + k0 + scol, (char*)Bs + chunk * 1024);
    }
    __syncthreads();
    #pragma unroll
    for (int kk = 0; kk < 2; ++kk) {
      bf16x8 af[4], bfr[4];
      #pragma unroll
      for (int i = 0; i < 4; ++i)
        af[i] = *reinterpret_cast<const bf16x8*>(
            &As[(wr*64 + i*16 + lr) * 64 + (((kk*4 + lk4) ^ lsw) * 8)]);
      #pragma unroll
      for (int i = 0; i < 4; ++i)
        bfr[i] = *reinterpret_cast<const bf16x8*>(
            &Bs[(wc*64 + i*16 + lr) * 64 + (((kk*4 + lk4) ^ lsw) * 8)]);
      #pragma unroll
      for (int mi = 0; mi < 4; ++mi)
        #pragma unroll
        for (int ni = 0; ni < 4; ++ni)
          acc[mi][ni] = __builtin_amdgcn_mfma_f32_16x16x32_bf16(af[mi], bfr[ni], acc[mi][ni], 0, 0, 0);
    }
  }

  __syncthreads();   // all waves done with As before overwriting it as comb
  // wc==1 waves hold p3 (w3 half); stash through LDS, wc==0 waves emit gated H
  if (wc == 1) {
    #pragma unroll
    for (int mi = 0; mi < 4; ++mi)
      #pragma unroll
      for (int ni = 0; ni < 4; ++ni)
        #pragma unroll
        for (int reg = 0; reg < 4; ++reg) {
          const int row = wr*64 + mi*16 + (lane >> 4) * 4 + reg;
          const int col = ni*16 + (lane & 15);
          comb[row * 64 + col] = (bf16)acc[mi][ni][reg];
        }
  }
  __syncthreads();
  if (wc == 0) {
    #pragma unroll
    for (int mi = 0; mi < 4; ++mi)
      #pragma unroll
      for (int ni = 0; ni < 4; ++ni)
        #pragma unroll
        for (int reg = 0; reg < 4; ++reg) {
          const int row = wr*64 + mi*16 + (lane >> 4) * 4 + reg;
          const int col = ni*16 + (lane & 15);
          float p3 = (float)comb[row * 64 + col];
          float p1 = acc[mi][ni][reg];
          H[(size_t)(m0 + row) * DFFN + bx * 64 + col] = (bf16)(p1 * sigmoidf_(p1) * p3);
        }
  }
}

// ---------------- narrow GEMM: 128x64 tile (N=768 GEMMs) ----------------
// EPI 0: momentum epilogue (vel = beta*vin + acc; x1 = x + vel -> outx, outv)
// EPI 1: C += acc (residual accumulate)
template <int EPI>
__global__ __launch_bounds__(256) void gemm_n64(
    const bf16* __restrict__ A, const bf16* __restrict__ Bt, float* __restrict__ C,
    const float* __restrict__ xin, const float* __restrict__ vin,
    float* __restrict__ outv, const float* __restrict__ log_beta,
    int M, int N, int K, int nx)
{
  __shared__ alignas(16) unsigned short As[128 * 64];   // 16 KB
  __shared__ alignas(16) unsigned short Bs[64 * 64];    //  8 KB

  const int wg = swz_wg();
  const int m0 = (wg / nx) * 128, n0 = (wg % nx) * 64;
  const int tid  = threadIdx.x;
  const int wave = tid >> 6;
  const int lane = tid & 63;
  const int wr = wave >> 1, wc = wave & 1;   // wave tile: 64 rows x 32 cols

  f32x4 acc[4][2] = {};
  const int srow = lane >> 3;
  const int scol = ((lane & 7) ^ srow) * 8;
  const int lr = lane & 15;
  const int lsw = lr & 7;
  const int lk4 = lane >> 4;

  for (int k0 = 0; k0 < K; k0 += 64) {
    __syncthreads();
    #pragma unroll
    for (int it = 0; it < 6; ++it) {
      const int chunk = wave * 6 + it;      // 0..23: 16 A-chunks then 8 B-chunks
      if (chunk < 16) {
        const int row = chunk * 8 + srow;
        gload_lds16(A + (size_t)(m0 + row) * K + k0 + scol, (char*)As + chunk * 1024);
      } else {
        const int row = (chunk - 16) * 8 + srow;
        gload_lds16(Bt + (size_t)(n0 + row) * K + k0 + scol, (char*)Bs + (chunk - 16) * 1024);
      }
    }
    __syncthreads();
    #pragma unroll
    for (int kk = 0; kk < 2; ++kk) {
      bf16x8 af[4], bfr[2];
      #pragma unroll
      for (int i = 0; i < 4; ++i)
        af[i] = *reinterpret_cast<const bf16x8*>(
            &As[(wr*64 + i*16 + lr) * 64 + (((kk*4 + lk4) ^ lsw) * 8)]);
      #pragma unroll
      for (int i = 0; i < 2; ++i)
        bfr[i] = *reinterpret_cast<const bf16x8*>(
            &Bs[(wc*32 + i*16 + lr) * 64 + (((kk*4 + lk4) ^ lsw) * 8)]);
      #pragma unroll
      for (int mi = 0; mi < 4; ++mi)
        #pragma unroll
        for (int ni = 0; ni < 2; ++ni)
          acc[mi][ni] = __builtin_amdgcn_mfma_f32_16x16x32_bf16(af[mi], bfr[ni], acc[mi][ni], 0, 0, 0);
    }
  }

  const float beta = (EPI == 0) ? sigmoidf_(log_beta[0]) : 0.f;
  #pragma unroll
  for (int mi = 0; mi < 4; ++mi)
    #pragma unroll
    for (int ni = 0; ni < 2; ++ni)
      #pragma unroll
      for (int reg = 0; reg < 4; ++reg) {
        const int r = m0 + wr*64 + mi*16 + (lane >> 4) * 4 + reg;
        const int c = n0 + wc*32 + ni*16 + (lane & 15);
        const size_t off = (size_t)r * N + c;
        float v = acc[mi][ni][reg];
        if (EPI == 0) {
          float vel = beta * vin[off] + v;
          float x1  = xin[off] + vel;
          outv[off] = vel;
          C[off] = x1;
        } else {
          C[off] += v;
        }
      }
}

// ---------------- RG-LRU 2-pass chunked scan (bf16 inputs) ----------------
#define NCH  32
#define CLEN 64   // TSEQ / NCH

__device__ __forceinline__ void lru_step(const bf16* row, int c, float coef,
                                         float& a, float& g)
{
  float v  = (float)row[2*DCONV + c];
  float r  = sigmoidf_((float)row[2*DCONV + DGRIF + c]);
  float is = sigmoidf_((float)row[2*DCONV + 2*DGRIF + c]);
  float la = coef * r;
  a = __expf(la);
  g = sqrtf(fmaxf(1.f - __expf(2.f * la), EPS_)) * (is * v);
}

__global__ __launch_bounds__(256) void lru_pass1(
    const bf16* __restrict__ g1, const float* __restrict__ lam,
    float* __restrict__ cA, float* __restrict__ cB)
{
  const int idx = blockIdx.x * 256 + threadIdx.x;   // < BSZ*NCH*DGRIF
  const int c = idx % DGRIF;
  const int rest = idx / DGRIF;
  const int j = rest & (NCH - 1);
  const int b = rest / NCH;
  const float coef = -8.f * log1pf(__expf(lam[c]));
  const bf16* base = g1 + (size_t)(b * TSEQ + j * CLEN) * NG1;
  float A = 1.f, Bv = 0.f;
  #pragma unroll 4
  for (int t = 0; t < CLEN; ++t) {
    float a, g;
    lru_step(base + (size_t)t * NG1, c, coef, a, g);
    A *= a;
    Bv = a * Bv + g;
  }
  cA[((size_t)b * DGRIF + c) * NCH + j] = A;
  cB[((size_t)b * DGRIF + c) * NCH + j] = Bv;
}

// pass2 also does the causal depthwise conv (K=3) * silu(g) for channel c:
// same (b, chunk, c) decomposition, walks t sequentially with a sliding window.
__global__ __launch_bounds__(256) void lru_pass2(
    const bf16* __restrict__ g1, const float* __restrict__ lam,
    const float* __restrict__ cA, const float* __restrict__ cB,
    const float* __restrict__ dw, bf16* __restrict__ mixin)
{
  const int idx = blockIdx.x * 256 + threadIdx.x;
  const int c = idx % DGRIF;
  const int rest = idx / DGRIF;
  const int j = rest & (NCH - 1);
  const int b = rest / NCH;
  const float coef = -8.f * log1pf(__expf(lam[c]));
  // lru carry from preceding chunks
  float Hc = 0.f;
  const float* pa = cA + ((size_t)b * DGRIF + c) * NCH;
  const float* pb = cB + ((size_t)b * DGRIF + c) * NCH;
  for (int k = 0; k < j; ++k) Hc = pa[k] * Hc + pb[k];

  const int t0 = j * CLEN;
  const bf16* base = g1 + (size_t)(b * TSEQ + t0) * NG1;
  // conv sliding-window lookback
  const float w0 = dw[c*3], w1 = dw[c*3 + 1], w2 = dw[c*3 + 2];
  float u1 = (t0 >= 1) ? (float)base[-(ptrdiff_t)NG1 + c]     : 0.f;
  float u0 = (t0 >= 2) ? (float)base[-(ptrdiff_t)(2*NG1) + c] : 0.f;

  bf16* mbase = mixin + (size_t)(b * TSEQ + t0) * DMOD;
  #pragma unroll 4
  for (int t = 0; t < CLEN; ++t) {
    const bf16* row = base + (size_t)t * NG1;
    // conv branch
    float u2 = (float)row[c];
    float gg = (float)row[DCONV + c];
    float conv = u0 * w0 + u1 * w1 + u2 * w2;
    mbase[(size_t)t * DMOD + c] = (bf16)(conv * (gg * sigmoidf_(gg)));
    u0 = u1; u1 = u2;
    // lru branch
    float a, g;
    lru_step(row, c, coef, a, g);
    Hc = a * Hc + g;
    mbase[(size_t)t * DMOD + DCONV + c] = (bf16)Hc;
  }
}

// ---------------- launcher ----------------
extern "C" void kernel_launch(void* const* d_in, const int* in_sizes, int n_in,
                              void* d_out, int out_size, void* d_ws, size_t ws_size,
                              hipStream_t stream)
{
  const float* x         = (const float*)d_in[0];
  const float* vel_in    = (const float*)d_in[1];
  const float* pre_w     = (const float*)d_in[2];
  const float* conv_in_w = (const float*)d_in[3];
  const float* conv_dw   = (const float*)d_in[4];
  const float* gv        = (const float*)d_in[5];
  const float* gr        = (const float*)d_in[6];
  const float* gi        = (const float*)d_in[7];
  const float* lam       = (const float*)d_in[8];
  const float* out_w     = (const float*)d_in[9];
  const float* log_beta  = (const float*)d_in[10];
  const float* ffn_w     = (const float*)d_in[11];
  const float* w1        = (const float*)d_in[12];
  const float* w3        = (const float*)d_in[13];
  const float* w2        = (const float*)d_in[14];

  char* ws = (char*)d_ws;
  size_t off = 0;
  auto alloc = [&](size_t bytes) { void* p = ws + off; off += (bytes + 255) & ~(size_t)255; return p; };

  bf16*  WT_G1  = (bf16*)alloc((size_t)NG1 * DMOD * 2);          // [1920][768]
  bf16*  WT_OUT = (bf16*)alloc((size_t)DMOD * DMOD * 2);         // [768][768]
  bf16*  WT_W13 = (bf16*)alloc((size_t)2 * DFFN * DMOD * 2);     // [4096][768] interleaved
  bf16*  WT_W2  = (bf16*)alloc((size_t)DMOD * DFFN * 2);         // [768][2048]
  float* CA     = (float*)alloc((size_t)BSZ * DGRIF * NCH * 4);
  float* CB     = (float*)alloc((size_t)BSZ * DGRIF * NCH * 4);
  bf16*  XN     = (bf16*)alloc((size_t)BT * DMOD * 2);           // 12.6 MB
  bf16*  G1     = (bf16*)alloc((size_t)BT * NG1 * 2);            // 31.5 MB
  bf16*  MIXIN  = (bf16*)alloc((size_t)BT * DMOD * 2);           // 12.6 MB
  bf16*  H      = (bf16*)alloc((size_t)BT * DFFN * 2);           // 33.6 MB
  bf16*  NORMED = (bf16*)alloc((size_t)BT * DMOD * 2);           // 12.6 MB

  float* OUTX   = (float*)d_out;
  float* OUTV   = OUTX + (size_t)BT * DMOD;

  const dim3 tb(32, 8);
  // weight transposes -> bf16 [N][K]
  transpose_bf16_kernel<0><<<dim3(DMOD/32,  DMOD/32), tb, 0, stream>>>(conv_in_w, WT_G1, DMOD, DMOD, 0);
  transpose_bf16_kernel<0><<<dim3(DGRIF/32, DMOD/32), tb, 0, stream>>>(gv, WT_G1 + (size_t)(2*DCONV) * DMOD, DMOD, DGRIF, 0);
  transpose_bf16_kernel<0><<<dim3(DGRIF/32, DMOD/32), tb, 0, stream>>>(gr, WT_G1 + (size_t)(2*DCONV + DGRIF) * DMOD, DMOD, DGRIF, 0);
  transpose_bf16_kernel<0><<<dim3(DGRIF/32, DMOD/32), tb, 0, stream>>>(gi, WT_G1 + (size_t)(2*DCONV + 2*DGRIF) * DMOD, DMOD, DGRIF, 0);
  transpose_bf16_kernel<0><<<dim3(DMOD/32,  DMOD/32), tb, 0, stream>>>(out_w, WT_OUT, DMOD, DMOD, 0);
  transpose_bf16_kernel<1><<<dim3(DFFN/32,  DMOD/32), tb, 0, stream>>>(w1, WT_W13, DMOD, DFFN, 0);
  transpose_bf16_kernel<1><<<dim3(DFFN/32,  DMOD/32), tb, 0, stream>>>(w3, WT_W13, DMOD, DFFN, 64);
  transpose_bf16_kernel<0><<<dim3(DMOD/32,  DFFN/32), tb, 0, stream>>>(w2, WT_W2, DFFN, DMOD, 0);

  // pre-norm
  rmsnorm_kernel<<<BT, 256, 0, stream>>>(x, pre_w, XN);

  // GEMM1: [8192,768] @ [768,1920] -> G1 (bf16)
  gemm_w128<<<(NG1/128) * (BT/128), 256, 0, stream>>>(XN, WT_G1, G1, BT, NG1, DMOD, NG1/128);

  // RG-LRU branch + fused conv branch -> MIXIN
  lru_pass1<<<(BSZ * NCH * DGRIF) / 256, 256, 0, stream>>>(G1, lam, CA, CB);
  lru_pass2<<<(BSZ * NCH * DGRIF) / 256, 256, 0, stream>>>(G1, lam, CA, CB, conv_dw, MIXIN);

  // GEMM2 + momentum epilogue: OUTX = x + vel, OUTV = vel
  gemm_n64<0><<<(DMOD/64) * (BT/128), 256, 0, stream>>>(MIXIN, WT_OUT, OUTX, x, vel_in, OUTV,
                                                        log_beta, BT, DMOD, DMOD, DMOD/64);

  // ffn rmsnorm on x1
  rmsnorm_kernel<<<BT, 256, 0, stream>>>(OUTX, ffn_w, NORMED);

  // fused FFN up-proj + SwiGLU gate -> H (bf16)
  gemm_ffn13<<<(DFFN/64) * (BT/128), 256, 0, stream>>>(NORMED, WT_W13, H, BT, DMOD, DFFN/64);

  // down-proj, accumulate into OUTX
  gemm_n64<1><<<(DMOD/64) * (BT/128), 256, 0, stream>>>(H, WT_W2, OUTX, nullptr, nullptr, nullptr,
                                                        nullptr, BT, DMOD, DFFN, DMOD/64);
}